// Round 1
// baseline (564.052 us; speedup 1.0000x reference)
//
#include <hip/hip_runtime.h>
#include <cstdint>

// ---------------------------------------------------------------------------
// SnLocalDecoder: B=4, n=48, C=32, two (SnConv2 -> LocalConv2 -> relu) layers
// + final SnConv2 (C_out=16). Everything factorizes over (b,m); fp32 only
// (no fp32 MFMA on CDNA4). Pipeline:
//   k_prep  : node_valid from mask diag (bool/int autodetect), S[b,c]
//   k_mix0  : layer-0 snconv2 small terms (closed form from x,S)
//   k_vw<0> : t0 on-the-fly from x -> s0 -> v,w      (W cols in VGPRs)
//   k_z     : z = V*W/n per (b,m); o-mix + relu + mask -> t
//   k_reduce: rows/cols/diag/tot from t (atomics for cols/tot)
//   k_mix   : generic snconv2 small terms
//   k_vw<1> : t -> s -> v,w
//   k_z, k_reduce, k_mix<16>, k_final -> d_out
// ---------------------------------------------------------------------------

namespace {

constexpr int nB = 4, nN = 48, nC = 32;
constexpr int SJ_ = nN * nC;            // 1536
constexpr int SI_ = nN * SJ_;           // 73728
constexpr long SB_ = (long)nN * SI_;    // 3538944
constexpr long NPOS_ = (long)nB * nN * nN * nN; // 442368

__device__ __forceinline__ void decodePos(int p, int& b, int& i, int& j, int& m) {
    m = p % nN; int r = p / nN;
    j = r % nN; r /= nN;
    i = r % nN; b = r / nN;
}

// ---------------------------------------------------------------------------
__global__ __launch_bounds__(256) void k_prep(const float* __restrict__ x,
                                              const void* __restrict__ maskp,
                                              float* __restrict__ vm,
                                              float* __restrict__ S)
{
    __shared__ float vmL[nB * nN];
    const int tid = threadIdx.x;
    const unsigned int w0 = *(const unsigned int*)maskp;
    const bool is_byte = (w0 == 0x01010101u);   // bool-byte layout (nodes 0..3 always valid)
    if (tid < nB * nN) {
        int b = tid / nN, i = tid % nN;
        long idx = ((long)(b * nN + i) * nN + i) * nN + i;   // mask[b,i,i,i] == valid_i
        int bit;
        if (is_byte) bit = (((const unsigned char*)maskp)[idx] != 0);
        else         bit = (((const int*)maskp)[idx] != 0);
        float f = bit ? 1.f : 0.f;
        vm[tid] = f; vmL[tid] = f;
    }
    __syncthreads();
    if (tid < nB * nC) {
        int b = tid >> 5, c = tid & 31;
        float s = 0.f;
        for (int j = 0; j < nN; ++j) s += x[(b * nN + j) * nC + c] * vmL[b * nN + j];
        S[tid] = s;
    }
}

// ---------------------------------------------------------------------------
// Layer-0 small snconv2 terms, closed form from x and S.
__global__ __launch_bounds__(256) void k_mix0(
    const float* __restrict__ x, const float* __restrict__ S,
    const float* __restrict__ Wb, const float* __restrict__ bias,
    float* __restrict__ drp, float* __restrict__ ccp, float* __restrict__ tbp)
{
    __shared__ float W2s[1024], W3s[1024], W4s[1024], W5s[1024], bs[32];
    const int tid = threadIdx.x;
    for (int q = tid; q < 1024; q += 256) {
        W2s[q] = Wb[2048 + q]; W3s[q] = Wb[3072 + q];
        W4s[q] = Wb[4096 + q]; W5s[q] = Wb[5120 + q];
    }
    if (tid < 32) bs[tid] = bias[tid];
    __syncthreads();
    const int id = blockIdx.x * 256 + tid;        // (b*48+i)*48+m
    const int m = id % nN; int r = id / nN; const int i = r % nN; const int b = r / nN;
    float odr[32], occ[32];
    #pragma unroll
    for (int d = 0; d < 32; ++d) { odr[d] = 0.f; occ[d] = 0.f; }
    for (int c2 = 0; c2 < 32; ++c2) {
        float xi = x[(b * nN + i) * nC + c2];
        float xm = x[(b * nN + m) * nC + c2];
        float sc = S[b * nC + c2];
        float A = xi * xi * xm;                   // diag coeff
        float R = xi * xm * sc * (1.f / nN);      // rows/cols coeff
        #pragma unroll
        for (int d = 0; d < 32; ++d) {
            odr[d] = fmaf(A, W2s[c2 * 32 + d], fmaf(R, W3s[c2 * 32 + d], odr[d]));
            occ[d] = fmaf(R, W4s[c2 * 32 + d], occ[d]);
        }
    }
    #pragma unroll
    for (int d = 0; d < 32; d += 4) {
        *(float4*)(drp + (size_t)id * 32 + d) = make_float4(odr[d], odr[d+1], odr[d+2], odr[d+3]);
        *(float4*)(ccp + (size_t)id * 32 + d) = make_float4(occ[d], occ[d+1], occ[d+2], occ[d+3]);
    }
    if (i == 0) {
        float ot[32];
        #pragma unroll
        for (int d = 0; d < 32; ++d) ot[d] = bs[d];
        for (int c2 = 0; c2 < 32; ++c2) {
            float xm = x[(b * nN + m) * nC + c2];
            float sc = S[b * nC + c2];
            float Tc = xm * sc * sc * (1.f / (nN * nN));
            #pragma unroll
            for (int d = 0; d < 32; ++d) ot[d] = fmaf(Tc, W5s[c2 * 32 + d], ot[d]);
        }
        for (int d = 0; d < 32; d += 4)
            *(float4*)(tbp + (size_t)(b * nN + m) * 32 + d) = make_float4(ot[d], ot[d+1], ot[d+2], ot[d+3]);
    }
}

// ---------------------------------------------------------------------------
// Generic small snconv2 terms from reductions.
template <int DOUT>
__global__ __launch_bounds__(256) void k_mix(
    const float* __restrict__ dgp, const float* __restrict__ rwp,
    const float* __restrict__ clp, const float* __restrict__ ttp,
    const float* __restrict__ Wb, const float* __restrict__ bias,
    float* __restrict__ drp, float* __restrict__ ccp, float* __restrict__ tbp)
{
    __shared__ float W2s[32 * DOUT], W3s[32 * DOUT], W4s[32 * DOUT], W5s[32 * DOUT], bs[DOUT];
    const int tid = threadIdx.x;
    for (int q = tid; q < 32 * DOUT; q += 256) {
        W2s[q] = Wb[2 * 32 * DOUT + q]; W3s[q] = Wb[3 * 32 * DOUT + q];
        W4s[q] = Wb[4 * 32 * DOUT + q]; W5s[q] = Wb[5 * 32 * DOUT + q];
    }
    if (tid < DOUT) bs[tid] = bias[tid];
    __syncthreads();
    const int id = blockIdx.x * 256 + tid;
    const int m = id % nN; int r = id / nN; const int i = r % nN; const int b = r / nN;
    float odr[DOUT], occ[DOUT];
    #pragma unroll
    for (int d = 0; d < DOUT; ++d) { odr[d] = 0.f; occ[d] = 0.f; }
    for (int c2 = 0; c2 < 32; ++c2) {
        float dg = dgp[(size_t)id * 32 + c2];
        float rw = rwp[(size_t)id * 32 + c2];
        float cl = clp[(size_t)id * 32 + c2];
        #pragma unroll
        for (int d = 0; d < DOUT; ++d) {
            odr[d] = fmaf(dg, W2s[c2 * DOUT + d], fmaf(rw, W3s[c2 * DOUT + d], odr[d]));
            occ[d] = fmaf(cl, W4s[c2 * DOUT + d], occ[d]);
        }
    }
    #pragma unroll
    for (int d = 0; d < DOUT; d += 4) {
        *(float4*)(drp + (size_t)id * DOUT + d) = make_float4(odr[d], odr[d+1], odr[d+2], odr[d+3]);
        *(float4*)(ccp + (size_t)id * DOUT + d) = make_float4(occ[d], occ[d+1], occ[d+2], occ[d+3]);
    }
    if (i == 0) {
        float ot[DOUT];
        #pragma unroll
        for (int d = 0; d < DOUT; ++d) ot[d] = bs[d];
        for (int c2 = 0; c2 < 32; ++c2) {
            float tv = ttp[(size_t)(b * nN + m) * 32 + c2];
            #pragma unroll
            for (int d = 0; d < DOUT; ++d) ot[d] = fmaf(tv, W5s[c2 * DOUT + d], ot[d]);
        }
        for (int d = 0; d < DOUT; d += 4)
            *(float4*)(tbp + (size_t)(b * nN + m) * DOUT + d) = make_float4(ot[d], ot[d+1], ot[d+2], ot[d+3]);
    }
}

// ---------------------------------------------------------------------------
// Reductions of t: rows (sum_j /n), cols (sum_i /n, atomic over i-blocks),
// diag, tot. Grid: (b*48+m)*4 + iq, block 256 = (jg in 8) x (c in 32).
__global__ __launch_bounds__(256) void k_reduce(
    const float* __restrict__ t,
    float* __restrict__ rows_, float* __restrict__ cols_,
    float* __restrict__ diag_, float* __restrict__ tot_)
{
    const int blk = blockIdx.x;
    const int iq = blk & 3; const int bm = blk >> 2;
    const int b = bm / nN, m = bm % nN;
    const int jg = threadIdx.x >> 5;
    const int c = threadIdx.x & 31;
    __shared__ float part[8][32];
    const size_t base = (size_t)b * SB_ + (size_t)m * nC;
    float colacc[6] = {0, 0, 0, 0, 0, 0};
    float totacc = 0.f;
    for (int ii = 0; ii < 12; ++ii) {
        const int i = iq * 12 + ii;
        float vals[6];
        #pragma unroll
        for (int jl = 0; jl < 6; ++jl) {
            int j = jg * 6 + jl;
            vals[jl] = t[base + (size_t)i * SI_ + (size_t)j * SJ_ + c];
        }
        float rp = 0.f;
        #pragma unroll
        for (int jl = 0; jl < 6; ++jl) { colacc[jl] += vals[jl]; rp += vals[jl]; }
        {
            int jd = i - jg * 6;
            if (jd >= 0 && jd < 6) diag_[((size_t)(b * nN + i) * nN + m) * nC + c] = vals[jd];
        }
        part[jg][c] = rp;
        __syncthreads();
        if (jg == 0) {
            float rv = 0.f;
            #pragma unroll
            for (int g = 0; g < 8; ++g) rv += part[g][c];
            rows_[((size_t)(b * nN + i) * nN + m) * nC + c] = rv * (1.f / nN);
            totacc += rv;
        }
        __syncthreads();
    }
    #pragma unroll
    for (int jl = 0; jl < 6; ++jl) {
        int j = jg * 6 + jl;
        atomicAdd(&cols_[((size_t)(b * nN + j) * nN + m) * nC + c], colacc[jl] * (1.f / nN));
    }
    if (jg == 0) atomicAdd(&tot_[(size_t)(b * nN + m) * nC + c], totacc * (1.f / (nN * nN)));
}

// ---------------------------------------------------------------------------
// s = masked(snconv2(t)); v = s@Wv+bv; w = s@Ww+bw.
// MODE 0: source is x (t0 = outer product, symmetric -> single sweep W0+W1).
// MODE 1: source is t (two sweeps: t with W0, t^T with W1).
// Thread map: 256 = (pt in 32: 4 consecutive positions) x (dq in 8: 4 d).
template <int MODE>
__global__ __launch_bounds__(256) void k_vw(
    const float* __restrict__ src, const float* __restrict__ vm,
    const float* __restrict__ drp, const float* __restrict__ ccp, const float* __restrict__ tbp,
    const float* __restrict__ W0, const float* __restrict__ W1,
    const float* __restrict__ Wv, const float* __restrict__ bv,
    const float* __restrict__ Ww, const float* __restrict__ bw,
    float* __restrict__ vout, float* __restrict__ wout)
{
    __shared__ float sA[128 * 34];
    __shared__ float sB[(MODE == 0) ? 64 : 128 * 34];
    __shared__ float sS[128 * 34];
    const int tid = threadIdx.x;
    const long base = (long)blockIdx.x * 128;

    if (MODE == 0) {
        for (int rep = 0; rep < 4; ++rep) {
            int q = rep * 256 + tid; int pl = q >> 3, cq = q & 7;
            int p = (int)base + pl;
            int b, i, j, m; decodePos(p, b, i, j, m);
            float4 xi = *(const float4*)(src + (size_t)(b * nN + i) * nC + cq * 4);
            float4 xj = *(const float4*)(src + (size_t)(b * nN + j) * nC + cq * 4);
            float4 xm = *(const float4*)(src + (size_t)(b * nN + m) * nC + cq * 4);
            int o = pl * 34 + cq * 4;
            sA[o + 0] = xi.x * xj.x * xm.x;
            sA[o + 1] = xi.y * xj.y * xm.y;
            sA[o + 2] = xi.z * xj.z * xm.z;
            sA[o + 3] = xi.w * xj.w * xm.w;
        }
    } else {
        for (int rep = 0; rep < 4; ++rep) {
            int q = rep * 256 + tid; int pl = q >> 3, cq = q & 7;
            long p = base + pl;
            float4 a = *(const float4*)(src + p * nC + cq * 4);
            int o = pl * 34 + cq * 4;
            sA[o + 0] = a.x; sA[o + 1] = a.y; sA[o + 2] = a.z; sA[o + 3] = a.w;
            int b, i, j, m; decodePos((int)p, b, i, j, m);
            long pT = ((long)(b * nN + j) * nN + i) * nN + m;
            float4 t4 = *(const float4*)(src + pT * nC + cq * 4);
            sB[o + 0] = t4.x; sB[o + 1] = t4.y; sB[o + 2] = t4.z; sB[o + 3] = t4.w;
        }
    }
    __syncthreads();

    const int pt = tid >> 3, dq = tid & 7;
    const int p0 = pt * 4, d0 = dq * 4;
    float wc[32][4];
    float acc[4][4];

    auto zeroAcc = [&]() {
        #pragma unroll
        for (int a2 = 0; a2 < 4; ++a2)
            #pragma unroll
            for (int l = 0; l < 4; ++l) acc[a2][l] = 0.f;
    };
    auto loadW = [&](const float* Wp) {
        #pragma unroll
        for (int c2 = 0; c2 < 32; ++c2) {
            float4 q4 = *(const float4*)(Wp + c2 * nC + d0);
            wc[c2][0] = q4.x; wc[c2][1] = q4.y; wc[c2][2] = q4.z; wc[c2][3] = q4.w;
        }
    };
    auto addW = [&](const float* Wp) {
        #pragma unroll
        for (int c2 = 0; c2 < 32; ++c2) {
            float4 q4 = *(const float4*)(Wp + c2 * nC + d0);
            wc[c2][0] += q4.x; wc[c2][1] += q4.y; wc[c2][2] += q4.z; wc[c2][3] += q4.w;
        }
    };
    auto sweep = [&](const float* sp) {
        #pragma unroll
        for (int c2 = 0; c2 < 32; ++c2) {
            float t0 = sp[(p0 + 0) * 34 + c2];
            float t1 = sp[(p0 + 1) * 34 + c2];
            float t2 = sp[(p0 + 2) * 34 + c2];
            float t3 = sp[(p0 + 3) * 34 + c2];
            #pragma unroll
            for (int l = 0; l < 4; ++l) {
                acc[0][l] = fmaf(t0, wc[c2][l], acc[0][l]);
                acc[1][l] = fmaf(t1, wc[c2][l], acc[1][l]);
                acc[2][l] = fmaf(t2, wc[c2][l], acc[2][l]);
                acc[3][l] = fmaf(t3, wc[c2][l], acc[3][l]);
            }
        }
    };

    zeroAcc();
    if (MODE == 0) { loadW(W0); addW(W1); sweep(sA); }
    else           { loadW(W0); sweep(sA); loadW(W1); sweep(sB); }

    // add small terms, mask, stash masked s
    #pragma unroll
    for (int l = 0; l < 4; ++l) {
        int p = (int)base + p0 + l;
        int b, i, j, m; decodePos(p, b, i, j, m);
        float4 d4 = *(const float4*)(drp + (size_t)((b * nN + i) * nN + m) * nC + d0);
        float4 c4 = *(const float4*)(ccp + (size_t)((b * nN + j) * nN + m) * nC + d0);
        float4 t4 = *(const float4*)(tbp + (size_t)(b * nN + m) * nC + d0);
        float mk = vm[b * nN + i] * vm[b * nN + j] * vm[b * nN + m];
        int o = (p0 + l) * 34 + d0;
        sS[o + 0] = (acc[l][0] + d4.x + c4.x + t4.x) * mk;
        sS[o + 1] = (acc[l][1] + d4.y + c4.y + t4.y) * mk;
        sS[o + 2] = (acc[l][2] + d4.z + c4.z + t4.z) * mk;
        sS[o + 3] = (acc[l][3] + d4.w + c4.w + t4.w) * mk;
    }
    __syncthreads();

    // stage B: v then w
    zeroAcc(); loadW(Wv); sweep(sS);
    {
        float4 b4 = *(const float4*)(bv + d0);
        #pragma unroll
        for (int l = 0; l < 4; ++l) {
            float4 o4 = make_float4(acc[l][0] + b4.x, acc[l][1] + b4.y,
                                    acc[l][2] + b4.z, acc[l][3] + b4.w);
            *(float4*)(vout + (size_t)(base + p0 + l) * nC + d0) = o4;
        }
    }
    zeroAcc(); loadW(Ww); sweep(sS);
    {
        float4 b4 = *(const float4*)(bw + d0);
        #pragma unroll
        for (int l = 0; l < 4; ++l) {
            float4 o4 = make_float4(acc[l][0] + b4.x, acc[l][1] + b4.y,
                                    acc[l][2] + b4.z, acc[l][3] + b4.w);
            *(float4*)(wout + (size_t)(base + p0 + l) * nC + d0) = o4;
        }
    }
}

// ---------------------------------------------------------------------------
// z[b,i,j,m,c] = sum_k v[b,i,k,m,c]*w[b,k,j,m,c]/n; out = relu(z@Wo+bo)*mask.
// Block: (b*48+m)*6 + it*2 + jt; tile i16 x j24, all 32 c.
__global__ __launch_bounds__(256) void k_z(
    const float* __restrict__ v, const float* __restrict__ w,
    const float* __restrict__ Wo, const float* __restrict__ bo,
    const float* __restrict__ vm, float* __restrict__ tout)
{
    __shared__ float lds[12416];   // Vt(8*545) + Wt(8*801) = 10768; z区 = 32*388
    const int tid = threadIdx.x;
    const int blk = blockIdx.x;
    const int tl = blk % 6; const int bm = blk / 6;
    const int it = tl >> 1, jt = tl & 1;
    const int b = bm / nN, m = bm % nN;
    const int c = tid & 31;
    const int jh = (tid >> 5) & 1;
    const int iq = tid >> 6;
    float* Vt = lds;
    float* Wt = lds + 8 * 545;
    const size_t posbase = (size_t)b * SB_ + (size_t)m * nC;
    float acc[4][12];
    #pragma unroll
    for (int l = 0; l < 4; ++l)
        #pragma unroll
        for (int u = 0; u < 12; ++u) acc[l][u] = 0.f;

    for (int kc = 0; kc < 6; ++kc) {
        __syncthreads();
        #pragma unroll
        for (int rr = 0; rr < 4; ++rr) {          // V tile: 16i x 8k x 32c
            int q = rr * 256 + tid; int pos = q >> 3, cq = q & 7;
            int ii = pos >> 3, kk = pos & 7;
            int gi = it * 16 + ii, gk = kc * 8 + kk;
            float4 a = *(const float4*)(v + posbase + (size_t)gi * SI_ + (size_t)gk * SJ_ + cq * 4);
            float* dst = Vt + kk * 545 + (cq * 4) * 17 + ii;
            dst[0] = a.x; dst[17] = a.y; dst[34] = a.z; dst[51] = a.w;
        }
        #pragma unroll
        for (int rr = 0; rr < 6; ++rr) {          // W tile: 8k x 24j x 32c
            int q = rr * 256 + tid; int pos = q >> 3, cq = q & 7;
            int kk = pos / 24, jj = pos % 24;
            int gk = kc * 8 + kk, gj = jt * 24 + jj;
            float4 a = *(const float4*)(w + posbase + (size_t)gk * SI_ + (size_t)gj * SJ_ + cq * 4);
            float* dst = Wt + kk * 801 + (cq * 4) * 25 + jj;
            dst[0] = a.x; dst[25] = a.y; dst[50] = a.z; dst[75] = a.w;
        }
        __syncthreads();
        #pragma unroll
        for (int kk = 0; kk < 8; ++kk) {
            float vf[4], wf[12];
            #pragma unroll
            for (int l = 0; l < 4; ++l) vf[l] = Vt[kk * 545 + c * 17 + iq * 4 + l];
            #pragma unroll
            for (int u = 0; u < 12; ++u) wf[u] = Wt[kk * 801 + c * 25 + jh * 12 + u];
            #pragma unroll
            for (int l = 0; l < 4; ++l)
                #pragma unroll
                for (int u = 0; u < 12; ++u)
                    acc[l][u] = fmaf(vf[l], wf[u], acc[l][u]);
        }
    }
    __syncthreads();
    #pragma unroll
    for (int l = 0; l < 4; ++l)
        #pragma unroll
        for (int u = 0; u < 12; ++u)
            lds[c * 388 + (iq * 4 + l) * 24 + jh * 12 + u] = acc[l][u];
    __syncthreads();

    // o-mix epilogue: 256 = (pt in 32: 12 positions) x (dq in 8: 4 d)
    const int pt = tid >> 3, dq = tid & 7, d0 = dq * 4;
    float wo[32][4];
    #pragma unroll
    for (int c2 = 0; c2 < 32; ++c2) {
        float4 q4 = *(const float4*)(Wo + c2 * nC + d0);
        wo[c2][0] = q4.x * (1.f / nN); wo[c2][1] = q4.y * (1.f / nN);
        wo[c2][2] = q4.z * (1.f / nN); wo[c2][3] = q4.w * (1.f / nN);
    }
    float4 b4 = *(const float4*)(bo + d0);
    float oac[12][4];
    #pragma unroll
    for (int u = 0; u < 12; ++u)
        #pragma unroll
        for (int l = 0; l < 4; ++l) oac[u][l] = 0.f;
    #pragma unroll
    for (int c2 = 0; c2 < 32; ++c2) {
        float zv[12];
        #pragma unroll
        for (int u = 0; u < 12; ++u) zv[u] = lds[c2 * 388 + pt * 12 + u];
        #pragma unroll
        for (int u = 0; u < 12; ++u)
            #pragma unroll
            for (int l = 0; l < 4; ++l)
                oac[u][l] = fmaf(zv[u], wo[c2][l], oac[u][l]);
    }
    const float vmm = vm[b * nN + m];
    #pragma unroll
    for (int u = 0; u < 12; ++u) {
        int pos = pt * 12 + u;
        int il = pos / 24, jl = pos % 24;
        int gi = it * 16 + il, gj = jt * 24 + jl;
        float mk = vm[b * nN + gi] * vm[b * nN + gj] * vmm;
        float4 o4;
        o4.x = fmaxf(oac[u][0] + b4.x, 0.f) * mk;
        o4.y = fmaxf(oac[u][1] + b4.y, 0.f) * mk;
        o4.z = fmaxf(oac[u][2] + b4.z, 0.f) * mk;
        o4.w = fmaxf(oac[u][3] + b4.w, 0.f) * mk;
        *(float4*)(tout + posbase + (size_t)gi * SI_ + (size_t)gj * SJ_ + d0) = o4;
    }
}

// ---------------------------------------------------------------------------
// Final snconv2 (C_out = 16), masked, direct to d_out.
__global__ __launch_bounds__(256) void k_final(
    const float* __restrict__ t, const float* __restrict__ vm,
    const float* __restrict__ drp, const float* __restrict__ ccp, const float* __restrict__ tbp,
    const float* __restrict__ W0, const float* __restrict__ W1,
    float* __restrict__ out)
{
    __shared__ float sA[128 * 34], sB[128 * 34];
    const int tid = threadIdx.x;
    const long base = (long)blockIdx.x * 128;
    for (int rep = 0; rep < 4; ++rep) {
        int q = rep * 256 + tid; int pl = q >> 3, cq = q & 7;
        long p = base + pl;
        float4 a = *(const float4*)(t + p * nC + cq * 4);
        int o = pl * 34 + cq * 4;
        sA[o + 0] = a.x; sA[o + 1] = a.y; sA[o + 2] = a.z; sA[o + 3] = a.w;
        int b, i, j, m; decodePos((int)p, b, i, j, m);
        long pT = ((long)(b * nN + j) * nN + i) * nN + m;
        float4 t4 = *(const float4*)(t + pT * nC + cq * 4);
        sB[o + 0] = t4.x; sB[o + 1] = t4.y; sB[o + 2] = t4.z; sB[o + 3] = t4.w;
    }
    __syncthreads();
    const int pt = tid >> 3, dq = tid & 7;
    const int p0 = pt * 4, d0 = dq * 2;
    float wc[32][2], acc[4][2];
    #pragma unroll
    for (int l = 0; l < 4; ++l) { acc[l][0] = 0.f; acc[l][1] = 0.f; }

    #pragma unroll
    for (int c2 = 0; c2 < 32; ++c2) {
        float2 q2 = *(const float2*)(W0 + c2 * 16 + d0);
        wc[c2][0] = q2.x; wc[c2][1] = q2.y;
    }
    #pragma unroll
    for (int c2 = 0; c2 < 32; ++c2) {
        float t0 = sA[(p0 + 0) * 34 + c2], t1 = sA[(p0 + 1) * 34 + c2];
        float t2 = sA[(p0 + 2) * 34 + c2], t3 = sA[(p0 + 3) * 34 + c2];
        acc[0][0] = fmaf(t0, wc[c2][0], acc[0][0]); acc[0][1] = fmaf(t0, wc[c2][1], acc[0][1]);
        acc[1][0] = fmaf(t1, wc[c2][0], acc[1][0]); acc[1][1] = fmaf(t1, wc[c2][1], acc[1][1]);
        acc[2][0] = fmaf(t2, wc[c2][0], acc[2][0]); acc[2][1] = fmaf(t2, wc[c2][1], acc[2][1]);
        acc[3][0] = fmaf(t3, wc[c2][0], acc[3][0]); acc[3][1] = fmaf(t3, wc[c2][1], acc[3][1]);
    }
    #pragma unroll
    for (int c2 = 0; c2 < 32; ++c2) {
        float2 q2 = *(const float2*)(W1 + c2 * 16 + d0);
        wc[c2][0] = q2.x; wc[c2][1] = q2.y;
    }
    #pragma unroll
    for (int c2 = 0; c2 < 32; ++c2) {
        float t0 = sB[(p0 + 0) * 34 + c2], t1 = sB[(p0 + 1) * 34 + c2];
        float t2 = sB[(p0 + 2) * 34 + c2], t3 = sB[(p0 + 3) * 34 + c2];
        acc[0][0] = fmaf(t0, wc[c2][0], acc[0][0]); acc[0][1] = fmaf(t0, wc[c2][1], acc[0][1]);
        acc[1][0] = fmaf(t1, wc[c2][0], acc[1][0]); acc[1][1] = fmaf(t1, wc[c2][1], acc[1][1]);
        acc[2][0] = fmaf(t2, wc[c2][0], acc[2][0]); acc[2][1] = fmaf(t2, wc[c2][1], acc[2][1]);
        acc[3][0] = fmaf(t3, wc[c2][0], acc[3][0]); acc[3][1] = fmaf(t3, wc[c2][1], acc[3][1]);
    }
    #pragma unroll
    for (int l = 0; l < 4; ++l) {
        int p = (int)base + p0 + l;
        int b, i, j, m; decodePos(p, b, i, j, m);
        float2 d2 = *(const float2*)(drp + (size_t)((b * nN + i) * nN + m) * 16 + d0);
        float2 cc2 = *(const float2*)(ccp + (size_t)((b * nN + j) * nN + m) * 16 + d0);
        float2 tb2 = *(const float2*)(tbp + (size_t)(b * nN + m) * 16 + d0);
        float mk = vm[b * nN + i] * vm[b * nN + j] * vm[b * nN + m];
        float2 o2;
        o2.x = (acc[l][0] + d2.x + cc2.x + tb2.x) * mk;
        o2.y = (acc[l][1] + d2.y + cc2.y + tb2.y) * mk;
        *(float2*)(out + (size_t)p * 16 + d0) = o2;
    }
}

} // anonymous namespace

// ---------------------------------------------------------------------------
extern "C" void kernel_launch(void* const* d_in, const int* in_sizes, int n_in,
                              void* d_out, int out_size, void* d_ws, size_t ws_size,
                              hipStream_t stream)
{
    (void)in_sizes; (void)n_in; (void)out_size; (void)ws_size;
    const float* x    = (const float*)d_in[0];
    const void*  mask = d_in[1];
    const float* bW0  = (const float*)d_in[2];
    const float* bb0  = (const float*)d_in[3];
    const float* lvW0 = (const float*)d_in[4];
    const float* lvb0 = (const float*)d_in[5];
    const float* lwW0 = (const float*)d_in[6];
    const float* lwb0 = (const float*)d_in[7];
    const float* loW0 = (const float*)d_in[8];
    const float* lob0 = (const float*)d_in[9];
    const float* bW1  = (const float*)d_in[10];
    const float* bb1  = (const float*)d_in[11];
    const float* lvW1 = (const float*)d_in[12];
    const float* lvb1 = (const float*)d_in[13];
    const float* lwW1 = (const float*)d_in[14];
    const float* lwb1 = (const float*)d_in[15];
    const float* loW1 = (const float*)d_in[16];
    const float* lob1 = (const float*)d_in[17];
    const float* fW   = (const float*)d_in[18];
    const float* fb   = (const float*)d_in[19];

    float* ws  = (float*)d_ws;                 // needs ~176 MB
    float* t   = ws;                           // 14155776
    float* v   = ws + 14155776L;
    float* w   = ws + 28311552L;
    float* rows = ws + 42467328L;              // 294912
    float* cols = rows + 294912;               // 294912
    float* diag = cols + 294912;               // 294912
    float* tot  = diag + 294912;               // 6144
    float* dr   = tot + 6144;                  // 294912
    float* cc   = dr + 294912;                 // 294912
    float* tb   = cc + 294912;                 // 6144
    float* S    = tb + 6144;                   // 128
    float* vm   = S + 128;                     // 192
    float* out  = (float*)d_out;

    k_prep<<<1, 256, 0, stream>>>(x, mask, vm, S);
    k_mix0<<<36, 256, 0, stream>>>(x, S, bW0, bb0, dr, cc, tb);
    k_vw<0><<<3456, 256, 0, stream>>>(x, vm, dr, cc, tb, bW0, bW0 + 1024,
                                      lvW0, lvb0, lwW0, lwb0, v, w);
    k_z<<<1152, 256, 0, stream>>>(v, w, loW0, lob0, vm, t);

    hipMemsetAsync(cols, 0, 294912 * sizeof(float), stream);
    hipMemsetAsync(tot, 0, 6144 * sizeof(float), stream);
    k_reduce<<<768, 256, 0, stream>>>(t, rows, cols, diag, tot);
    k_mix<32><<<36, 256, 0, stream>>>(diag, rows, cols, tot, bW1, bb1, dr, cc, tb);
    k_vw<1><<<3456, 256, 0, stream>>>(t, vm, dr, cc, tb, bW1, bW1 + 1024,
                                      lvW1, lvb1, lwW1, lwb1, v, w);
    k_z<<<1152, 256, 0, stream>>>(v, w, loW1, lob1, vm, t);

    hipMemsetAsync(cols, 0, 294912 * sizeof(float), stream);
    hipMemsetAsync(tot, 0, 6144 * sizeof(float), stream);
    k_reduce<<<768, 256, 0, stream>>>(t, rows, cols, diag, tot);
    k_mix<16><<<36, 256, 0, stream>>>(diag, rows, cols, tot, fW, fb, dr, cc, tb);
    k_final<<<3456, 256, 0, stream>>>(t, vm, dr, cc, tb, fW, fW + 512, out);
}